// Round 5
// baseline (2710.594 us; speedup 1.0000x reference)
//
#include <hip/hip_runtime.h>

// DTW accumulated-cost, output = last column. N=65536 rows (input), K=512 cols (kernel).
//
// R7: R6's 8-wave / 1-column-per-lane / all-register dataflow, with the ring
// discipline reverted to the R5-verified form. R6 failed (absmax=inf): 2 chunks
// per barrier on a 4-chunk ring let the producer overwrite the consumer's wrap
// slot in the same interval (chunk 2P+3 = 2P-1 mod 4) -> INF into the bk FIFO
// at lane 0 poisons the band permanently (matches the inf signature). R7 runs
// 1 chunk per barrier: consumer reads slots {(c-1)&3, c&3}, producer writes
// (c+1)&3 -- disjoint under any wave drift, same proof as R2-R5.
// Kept from R6:
//  - j = 64*w + lane (8 waves, 2 per SIMD): TLP hides DPP hazards/ds latency.
//  - x rides a DPP shift FIFO (lane L's x at diag t+1 == lane L-1's x at diag t);
//    ONE coalesced global_load_dword per wave per 64-diag chunk.
//  - boundary/keep share one DPP FIFO (consume lane0 via dpp-old, insert lane63).
//  - inner iter = 8 VALU ops (4 dpp + sub + fma + 2 fmin), zero memory.
// Recurrence: A_t[j] = min(A_{t-1}[j], E_{t-1}[j-1]) + (k[j]-x[t-j])^2,
//             E_t[j] = min(A_t[j], A_{t-1}[j]).  Output = A at j=511 (wave7 lane63).

#define K_LEN 512
#define N_LEN 65536
#define PAD_L 512
#define PAD_R 1024
#define XPAD_TOTAL (PAD_L + N_LEN + PAD_R) // 67072 floats = 268288 B of d_ws
#define BIGX 1e20f
#define NCHUNK 1032                        // 1032*64 = 66048 >= N+K-1 = 66047 diagonals
#define RING 256                           // ring entries per boundary buffer (4 chunks)
#define NW 8

__global__ void dtw_pad_kernel(const float* __restrict__ x, float* __restrict__ xpad) {
    int i = blockIdx.x * blockDim.x + threadIdx.x;
    if (i < XPAD_TOTAL) {
        int j = i - PAD_L;
        xpad[i] = (j >= 0 && j < N_LEN) ? x[j] : BIGX;
    }
}

// lane l <- lane l-1 of src; lane 0 <- old[0]        (dpp 0x138, bound_ctrl=0; HW-verified R2-R5)
__device__ __forceinline__ float dpp_wave_shr1(float oldv, float src) {
    return __int_as_float(__builtin_amdgcn_update_dpp(
        __float_as_int(oldv), __float_as_int(src), 0x138, 0xF, 0xF, false));
}
// lane l <- lane l+1 of src; lane 63 <- old[63]      (dpp 0x130, bound_ctrl=0; HW-verified R5)
__device__ __forceinline__ float dpp_wave_shl1(float oldv, float src) {
    return __int_as_float(__builtin_amdgcn_update_dpp(
        __float_as_int(oldv), __float_as_int(src), 0x130, 0xF, 0xF, false));
}

#define BARRIER() asm volatile("s_waitcnt lgkmcnt(0)\n\ts_barrier" ::: "memory")

// One 64-diagonal chunk. bk: merged FIFO (lane0 = boundary for current iter via
// dpp-old; keep value inserted at lane63 -> after 64 iters lane r = iter-r keep).
// xf: x FIFO (lane r = the x entering lane0 at iter r). xc: current x per lane.
template <bool LAST>
__device__ __forceinline__ float chunk64(float bk, float xf, float& xc,
                                         float& A, float& E, float k) {
#pragma unroll
    for (int r = 0; r < 64; ++r) {
        xc = dpp_wave_shr1(xf, xc);             // x shifts 1 lane per diagonal
        xf = dpp_wave_shl1(xf, xf);             // pop FIFO head
        const float esh = dpp_wave_shr1(bk, E); // E[j-1]; lane0 <- boundary
        const float tv  = k - xc;
        const float nA  = __builtin_fmaf(tv, tv, fminf(A, esh));
        const float nE  = fminf(nA, A);
        bk = dpp_wave_shl1(LAST ? nA : nE, bk); // insert keep at lane63
        A = nA; E = nE;
    }
    return bk;
}

template <bool LAST>
__device__ __forceinline__ void run_all(const float* __restrict__ xb,
                                        const float* __restrict__ ldsIn,
                                        float* __restrict__ ldsOut,
                                        float* __restrict__ lds,
                                        float k, int lane, int tid,
                                        float* __restrict__ out) {
    const float INFV = __builtin_inff();
    float xc = BIGX;                 // x entering t=0 is all pad (indices < 0)
    float A = INFV, E = INFV;
    float fcur = xb[0];              // chunk 0's x FIFO

    for (int c = 0; c < NCHUNK; ++c) {
        const int rb = (c & 3) << 6;
        const float fnext = xb[(c + 1) * 64];   // next chunk's FIFO (1 dword, L1-resident)
        float bk = ldsIn[(rb + lane - 1) & (RING - 1)]; // boundary; lane0 wraps to prev chunk
        bk = chunk64<LAST>(bk, fcur, xc, A, E, k);
        if (!LAST) {
            ldsOut[rb + lane] = bk;                    // single ds_write_b32
        } else {
            const int oi = c * 64 + lane - (K_LEN - 1);
            if (oi >= 0 && oi < N_LEN) out[oi] = bk;   // coalesced chunk output
        }
        if (c == 0 && tid == 0) lds[7 * RING + RING - 1] = INFV; // retire DP seed
        BARRIER();                  // LDS-only drain; x loads/stores stay in flight
        fcur = fnext;
    }
}

__global__ __launch_bounds__(512, 1) void dtw_main(const float* __restrict__ xpad,
                                                   const float* __restrict__ kern,
                                                   float* __restrict__ out) {
    // rings 0..6: boundary keep of waves 0..6; ring 7: INIT (wave0's input),
    // all INF except INIT[255] = 0.0 = DP seed ac[-1][-1] (wave0 chunk0 iter0).
    __shared__ float lds[NW * RING];
    const float INFV = __builtin_inff();
    const int tid  = threadIdx.x;
    const int w    = __builtin_amdgcn_readfirstlane(tid) >> 6; // wave id, uniform SGPR
    const int lane = tid & 63;

    for (int i = tid; i < NW * RING; i += 512)
        lds[i] = (i == 7 * RING + RING - 1) ? 0.0f : INFV;
    __syncthreads();

    const float k = kern[w * 64 + lane];    // this lane's column j = 64w + lane
    // x FIFO source: for chunk c, lane p loads x[64c + p - 64w]
    const float* xb = xpad + (PAD_L - w * 64) + lane;

    float* ldsOut      = lds + w * RING;    // wave7 never writes (LAST path)
    const float* ldsIn = (w == 0) ? (lds + 7 * RING) : (lds + (w - 1) * RING);

    for (int b = 0; b < w; ++b) BARRIER();  // skew intro: wave w starts chunk 0 at superstep w

    if (w == 7)
        run_all<true >(xb, ldsIn, ldsOut, lds, k, lane, tid, out);
    else
        run_all<false>(xb, ldsIn, ldsOut, lds, k, lane, tid, out);

    for (int b = 0; b < 7 - w; ++b) BARRIER(); // drain: every wave executes 1039 barriers

    (void)INFV;
}

extern "C" void kernel_launch(void* const* d_in, const int* in_sizes, int n_in,
                              void* d_out, int out_size, void* d_ws, size_t ws_size,
                              hipStream_t stream) {
    const float* x = (const float*)d_in[0];   // input, 65536 fp32
    const float* k = (const float*)d_in[1];   // kernel, 512 fp32
    float* xpad = (float*)d_ws;               // needs 268288 B of scratch
    float* out  = (float*)d_out;              // 65536 fp32
    dtw_pad_kernel<<<(XPAD_TOTAL + 255) / 256, 256, 0, stream>>>(x, xpad);
    dtw_main<<<1, 512, 0, stream>>>(xpad, k, out);
}

// Round 7
// 2536.000 us; speedup vs baseline: 1.0688x; 1.0688x over previous
//
#include <hip/hip_runtime.h>

// DTW accumulated-cost, output = last column. N=65536 rows (input), K=512 cols (kernel).
//
// R9 = R7 layout x R5 load engine, per the re-fit cost model:
//   R7 (8w, 2/SIMD, 4 DPP+4 VALU/col) = 24cy/iter issue-bound, VALUBusy 99% ->
//     DPP ~ 4cy, VALU ~ 2cy (R8's 8-16cy DPP estimate was wrong).
//   R5 (4w, 1/SIMD, issue 22cy/iter) measured 83cy/iter -> ~60cy exposed
//     dependent-chain latency; 1 wave/SIMD cannot hide it.
// => need 2 waves/SIMD (TLP hides the chain) AND minimal DPP count. R7's extra
//    cost was the x-FIFO (2 of its 4 DPPs). Replace it with R5's asm-batched
//    per-lane x loads (16 scalar dwords per sub-block, counted vmcnt(16), 2-batch
//    prefetch distance). Inner iter = 2 DPP + 4 VALU, zero memory in the chain.
// Kept verbatim from R7 (HW-verified pass): 8 waves j=64w+lane, merged
// boundary/keep DPP FIFO, 4-chunk LDS rings, 1 chunk/barrier, seed handling.
// Kept verbatim from R5 (HW-verified pass): asm volatile load batches +
// s_waitcnt vmcnt(16) + sched_barrier(0) discipline.
// (R8's __builtin_amdgcn_writelane does not exist on this ROCm - path dropped.)

#define K_LEN 512
#define N_LEN 65536
#define PAD_L 512
#define PAD_R 1024
#define XPAD_TOTAL (PAD_L + N_LEN + PAD_R) // 67072 floats = 268288 B of d_ws
#define BIGX 1e20f
#define NCHUNK 1032                        // 1032*64 = 66048 >= N+K-1 = 66047 diagonals
#define RING 256                           // ring entries per boundary buffer (4 chunks)
#define NW 8

__global__ void dtw_pad_kernel(const float* __restrict__ x, float* __restrict__ xpad) {
    int i = blockIdx.x * blockDim.x + threadIdx.x;
    if (i < XPAD_TOTAL) {
        int j = i - PAD_L;
        xpad[i] = (j >= 0 && j < N_LEN) ? x[j] : BIGX;
    }
}

// lane l <- lane l-1 of src; lane 0 <- old[0]   (dpp 0x138 wave_shr:1, bound_ctrl=0; verified)
__device__ __forceinline__ float dpp_wave_shr1(float oldv, float src) {
    return __int_as_float(__builtin_amdgcn_update_dpp(
        __float_as_int(oldv), __float_as_int(src), 0x138, 0xF, 0xF, false));
}
// lane l <- lane l+1 of src; lane 63 <- old[63] (dpp 0x130 wave_shl:1, bound_ctrl=0; verified)
__device__ __forceinline__ float dpp_wave_shl1(float oldv, float src) {
    return __int_as_float(__builtin_amdgcn_update_dpp(
        __float_as_int(oldv), __float_as_int(src), 0x130, 0xF, 0xF, false));
}

#define BARRIER() asm volatile("s_waitcnt lgkmcnt(0)\n\ts_barrier" ::: "memory")
// counted VMEM wait: all but the newest 16-load batch retired, then a hard
// scheduling fence so register-only iters cannot hoist above it (rule #18)
#define WAITV16() do { asm volatile("s_waitcnt vmcnt(16)" ::: "memory"); \
                       __builtin_amdgcn_sched_barrier(0); } while (0)

struct XB16 { float v[16]; }; // one 16-iter sub-block of the per-lane x stream

// 16 scalar dwords in one non-movable asm block (per-lane stream, 1 col/lane ->
// arbitrary alignment, dword granularity).
__device__ __forceinline__ void load_sb16(XB16& b, const float* p) {
    asm volatile(
        "global_load_dword %0,  %[ad], off\n\t"
        "global_load_dword %1,  %[ad], off offset:4\n\t"
        "global_load_dword %2,  %[ad], off offset:8\n\t"
        "global_load_dword %3,  %[ad], off offset:12\n\t"
        "global_load_dword %4,  %[ad], off offset:16\n\t"
        "global_load_dword %5,  %[ad], off offset:20\n\t"
        "global_load_dword %6,  %[ad], off offset:24\n\t"
        "global_load_dword %7,  %[ad], off offset:28\n\t"
        "global_load_dword %8,  %[ad], off offset:32\n\t"
        "global_load_dword %9,  %[ad], off offset:36\n\t"
        "global_load_dword %10, %[ad], off offset:40\n\t"
        "global_load_dword %11, %[ad], off offset:44\n\t"
        "global_load_dword %12, %[ad], off offset:48\n\t"
        "global_load_dword %13, %[ad], off offset:52\n\t"
        "global_load_dword %14, %[ad], off offset:56\n\t"
        "global_load_dword %15, %[ad], off offset:60"
        : "=v"(b.v[0]),  "=v"(b.v[1]),  "=v"(b.v[2]),  "=v"(b.v[3]),
          "=v"(b.v[4]),  "=v"(b.v[5]),  "=v"(b.v[6]),  "=v"(b.v[7]),
          "=v"(b.v[8]),  "=v"(b.v[9]),  "=v"(b.v[10]), "=v"(b.v[11]),
          "=v"(b.v[12]), "=v"(b.v[13]), "=v"(b.v[14]), "=v"(b.v[15])
        : [ad] "v"(p)
        : "memory");
}

template <bool LAST>
__device__ __forceinline__ void run_all(const float* __restrict__ xl,
                                        const float* __restrict__ ldsIn,
                                        float* __restrict__ ldsOut,
                                        float* __restrict__ lds,
                                        float k, int lane, int tid,
                                        float* __restrict__ out) {
    const float INFV = __builtin_inff();
    float A = INFV, E = INFV;
    float bk; // merged FIFO: lane0 = boundary for current iter (consumed via
              // dpp-old of the E-shift); keep inserted at lane63; after 64
              // iters lane r holds the iter-r keep value.

    auto ITER = [&](float xf) {
        const float esh = dpp_wave_shr1(bk, E);  // E[j-1]; lane0 <- bk[0]
        const float tv  = k - xf;
        const float nA  = __builtin_fmaf(tv, tv, fminf(A, esh));
        const float nE  = fminf(nA, A);
        bk = dpp_wave_shl1(LAST ? nA : nE, bk);  // pop head, insert keep at 63
        A = nA; E = nE;
    };
    XB16 b0, b1, b2, b3;
    auto COMPUTE = [&](const XB16& b) {
#pragma unroll
        for (int q = 0; q < 16; ++q) ITER(b.v[q]);
    };

    load_sb16(b0, xl);       // chunk0 sub-block 0
    load_sb16(b1, xl + 16);  // chunk0 sub-block 1

    for (int c = 0; c < NCHUNK; ++c) {
        const int t0 = c * 64;
        const int rb = (c & 3) << 6;
        bk = ldsIn[(rb + lane - 1) & (RING - 1)]; // boundary; lane0 wraps to prev chunk

        load_sb16(b2, xl + t0 + 32); WAITV16(); COMPUTE(b0); // pos0
        load_sb16(b3, xl + t0 + 48); WAITV16(); COMPUTE(b1); // pos1
        load_sb16(b0, xl + t0 + 64); WAITV16(); COMPUTE(b2); // pos2 (next chunk sb0)
        load_sb16(b1, xl + t0 + 80); WAITV16(); COMPUTE(b3); // pos3 (next chunk sb1)

        if (!LAST) {
            ldsOut[rb + lane] = bk;                    // single ds_write_b32
        } else {
            const int oi = t0 + lane - (K_LEN - 1);
            if (oi >= 0 && oi < N_LEN) out[oi] = bk;   // coalesced chunk output
        }
        if (c == 0 && tid == 0) lds[7 * RING + RING - 1] = INFV; // retire DP seed
        BARRIER(); // LDS-only drain; x loads / wave7 store stay in flight
    }
}

__global__ __launch_bounds__(512, 1) void dtw_main(const float* __restrict__ xpad,
                                                   const float* __restrict__ kern,
                                                   float* __restrict__ out) {
    // rings 0..6: boundary keep of waves 0..6; ring 7: INIT (wave0's input),
    // all INF except INIT[255] = 0.0 = DP seed ac[-1][-1] (wave0 chunk0 iter0).
    __shared__ float lds[NW * RING];
    const float INFV = __builtin_inff();
    const int tid  = threadIdx.x;
    const int w    = __builtin_amdgcn_readfirstlane(tid) >> 6; // wave id, uniform SGPR
    const int lane = tid & 63;

    for (int i = tid; i < NW * RING; i += 512)
        lds[i] = (i == 7 * RING + RING - 1) ? 0.0f : INFV;
    __syncthreads();

    const float k = kern[w * 64 + lane];    // this lane's column j = 64w + lane
    // per-lane x stream: at diagonal t this lane needs x[t - j] = xl[t]
    const float* xl = xpad + (PAD_L - (w * 64 + lane));

    float* ldsOut      = lds + w * RING;    // wave7 never writes (LAST path)
    const float* ldsIn = (w == 0) ? (lds + 7 * RING) : (lds + (w - 1) * RING);

    for (int b = 0; b < w; ++b) BARRIER();  // skew intro: wave w starts chunk 0 at superstep w

    if (w == 7)
        run_all<true >(xl, ldsIn, ldsOut, lds, k, lane, tid, out);
    else
        run_all<false>(xl, ldsIn, ldsOut, lds, k, lane, tid, out);

    for (int b = 0; b < 7 - w; ++b) BARRIER(); // drain: every wave executes 1039 barriers

    (void)INFV;
}

extern "C" void kernel_launch(void* const* d_in, const int* in_sizes, int n_in,
                              void* d_out, int out_size, void* d_ws, size_t ws_size,
                              hipStream_t stream) {
    const float* x = (const float*)d_in[0];   // input, 65536 fp32
    const float* k = (const float*)d_in[1];   // kernel, 512 fp32
    float* xpad = (float*)d_ws;               // needs 268288 B of scratch
    float* out  = (float*)d_out;              // 65536 fp32
    dtw_pad_kernel<<<(XPAD_TOTAL + 255) / 256, 256, 0, stream>>>(x, xpad);
    dtw_main<<<1, 512, 0, stream>>>(xpad, k, out);
}